// Round 12
// baseline (196.073 us; speedup 1.0000x reference)
//
#include <hip/hip_runtime.h>
#include <hip/hip_bf16.h>
#include <math.h>

typedef __hip_bfloat16 bf16;
typedef __attribute__((ext_vector_type(8))) short bf16x8;
typedef __attribute__((ext_vector_type(4))) float f32x4;

#define B_   256
#define NPG_ 200
#define N0_  (B_*NPG_)     // 51200
#define DEGC 16
#define E_   (N0_*DEGC)    // 819200
#define SLOTG (NPG_*DEGC)  // 3200 edge slots per graph (original layout, never moved)
#define CSTRIDE 4096       // padded CSR slots per graph
#define CSRN (B_*CSTRIDE)
#define FIN_ 128
#define H_   256
#define K1_  100
#define K2_  50
#define K3_  25

// bijective XCD-chunk swizzle (m204)
__device__ __forceinline__ int xcd_swz(int bid, int nwg) {
    int q = nwg >> 3, r = nwg & 7;
    int x = bid & 7, j = bid >> 3;
    return (x < r ? x * (q + 1) : r * (q + 1) + (x - r) * q) + j;
}

__device__ __forceinline__ unsigned int bfu(bf16 h) {
    return (unsigned int)*reinterpret_cast<unsigned short*>(&h);
}
__device__ __forceinline__ void write_split2(bf16* AH, bf16* AL, size_t idx, float a, float b) {
    bf16 h0 = __float2bfloat16(a), h1 = __float2bfloat16(b);
    bf16 l0 = __float2bfloat16(a - __bfloat162float(h0));
    bf16 l1 = __float2bfloat16(b - __bfloat162float(h1));
    *(unsigned int*)&AH[idx] = bfu(h0) | (bfu(h1) << 16);
    *(unsigned int*)&AL[idx] = bfu(l0) | (bfu(l1) << 16);
}
__device__ __forceinline__ void write_split4(bf16* AH, bf16* AL, size_t idx,
                                             float a, float b, float c, float d) {
    bf16 h0 = __float2bfloat16(a), h1 = __float2bfloat16(b);
    bf16 h2 = __float2bfloat16(c), h3 = __float2bfloat16(d);
    uint2 hh, ll;
    hh.x = bfu(h0) | (bfu(h1) << 16);
    hh.y = bfu(h2) | (bfu(h3) << 16);
    ll.x = bfu(__float2bfloat16(a - __bfloat162float(h0))) |
           (bfu(__float2bfloat16(b - __bfloat162float(h1))) << 16);
    ll.y = bfu(__float2bfloat16(c - __bfloat162float(h2))) |
           (bfu(__float2bfloat16(d - __bfloat162float(h3))) << 16);
    *(uint2*)&AH[idx] = hh;
    *(uint2*)&AL[idx] = ll;
}

// ---- batched W convert: W[K][N] f32 -> WT hi/lo bf16 [N][K], all 3 stages ----
__global__ void wconv_k(const float* __restrict__ W1, const float* __restrict__ W2,
                        const float* __restrict__ W3, bf16* __restrict__ THb,
                        bf16* __restrict__ TLb) {
    __shared__ float tile[32][33];
    int st = blockIdx.z;
    const float* W = st == 0 ? W1 : (st == 1 ? W2 : W3);
    int K = st == 0 ? 128 : 256;
    int N = 256;
    int k0 = blockIdx.x * 32, n0 = blockIdx.y * 32;
    if (k0 >= K) return;
    bf16* TH = THb + st * 65536;
    bf16* TL = TLb + st * 65536;
    int t = threadIdx.x;
    int tc = t & 31, tr = t >> 5;
    #pragma unroll
    for (int i = 0; i < 4; i++) {
        int kk = tr + i * 8;
        tile[kk][tc] = W[(size_t)(k0 + kk) * N + n0 + tc];
    }
    __syncthreads();
    #pragma unroll
    for (int i = 0; i < 4; i++) {
        int nn = tr + i * 8;
        float v = tile[tc][nn];
        bf16 h = __float2bfloat16(v);
        TH[(size_t)(n0 + nn) * K + k0 + tc] = h;
        TL[(size_t)(n0 + nn) * K + k0 + tc] = __float2bfloat16(v - __bfloat162float(h));
    }
}

// ---- MFMA split-bf16 GEMM: C = relu(A@W + bias), fused partial h.Ws dots ----
__global__ __launch_bounds__(256) void gemm_mfma(
        const bf16* __restrict__ AH, const bf16* __restrict__ AL,
        const bf16* __restrict__ BTH, const bf16* __restrict__ BTL,
        const float* __restrict__ bias, const float* __restrict__ Wsd,
        float* __restrict__ C, float* __restrict__ xsp, int M, int K, int N) {
    __shared__ bf16 lAh[64 * 40], lAl[64 * 40];
    __shared__ bf16 lBh[128 * 40], lBl[128 * 40];
    int t = threadIdx.x;
    int w = t >> 6, l = t & 63;
    int wr = w >> 1, wc = w & 1;
    int bm = xcd_swz(blockIdx.x, gridDim.x) * 64;
    int bn = blockIdx.y * 128;
    int srow = t >> 2, skg = (t & 3) * 8;
    f32x4 acc[2][4] = {};
    int coll = l & 15, kg8 = (l >> 4) * 8;
    for (int k0 = 0; k0 < K; k0 += 32) {
        *(uint4*)&lAh[srow * 40 + skg] = *(const uint4*)&AH[(size_t)(bm + srow) * K + k0 + skg];
        *(uint4*)&lAl[srow * 40 + skg] = *(const uint4*)&AL[(size_t)(bm + srow) * K + k0 + skg];
        *(uint4*)&lBh[srow * 40 + skg]        = *(const uint4*)&BTH[(size_t)(bn + srow) * K + k0 + skg];
        *(uint4*)&lBh[(64 + srow) * 40 + skg] = *(const uint4*)&BTH[(size_t)(bn + 64 + srow) * K + k0 + skg];
        *(uint4*)&lBl[srow * 40 + skg]        = *(const uint4*)&BTL[(size_t)(bn + srow) * K + k0 + skg];
        *(uint4*)&lBl[(64 + srow) * 40 + skg] = *(const uint4*)&BTL[(size_t)(bn + 64 + srow) * K + k0 + skg];
        __syncthreads();
        bf16x8 ah[2], al[2], bh[4], bl[4];
        #pragma unroll
        for (int rt = 0; rt < 2; rt++) {
            int row = wr * 32 + rt * 16 + coll;
            ah[rt] = *(const bf16x8*)&lAh[row * 40 + kg8];
            al[rt] = *(const bf16x8*)&lAl[row * 40 + kg8];
        }
        #pragma unroll
        for (int ct = 0; ct < 4; ct++) {
            int col = wc * 64 + ct * 16 + coll;
            bh[ct] = *(const bf16x8*)&lBh[col * 40 + kg8];
            bl[ct] = *(const bf16x8*)&lBl[col * 40 + kg8];
        }
        #pragma unroll
        for (int rt = 0; rt < 2; rt++)
            #pragma unroll
            for (int ct = 0; ct < 4; ct++) {
                acc[rt][ct] = __builtin_amdgcn_mfma_f32_16x16x32_bf16(ah[rt], bh[ct], acc[rt][ct], 0, 0, 0);
                acc[rt][ct] = __builtin_amdgcn_mfma_f32_16x16x32_bf16(ah[rt], bl[ct], acc[rt][ct], 0, 0, 0);
                acc[rt][ct] = __builtin_amdgcn_mfma_f32_16x16x32_bf16(al[rt], bh[ct], acc[rt][ct], 0, 0, 0);
            }
        __syncthreads();
    }
    int gq = l >> 4;
    float bb[4], wv[4];
    #pragma unroll
    for (int ct = 0; ct < 4; ct++) {
        int col = bn + wc * 64 + ct * 16 + coll;
        bb[ct] = bias[col];
        wv[ct] = Wsd[col];
    }
    #pragma unroll
    for (int rt = 0; rt < 2; rt++) {
        int rowb = bm + wr * 32 + rt * 16 + gq * 4;
        float pr[4] = {0.f, 0.f, 0.f, 0.f};
        #pragma unroll
        for (int ct = 0; ct < 4; ct++) {
            int col = bn + wc * 64 + ct * 16 + coll;
            #pragma unroll
            for (int r = 0; r < 4; r++) {
                float v = fmaxf(acc[rt][ct][r] + bb[ct], 0.f);
                C[(size_t)(rowb + r) * N + col] = v;
                pr[r] += v * wv[ct];
            }
        }
        #pragma unroll
        for (int r = 0; r < 4; r++) {
            pr[r] += __shfl_xor(pr[r], 1); pr[r] += __shfl_xor(pr[r], 2);
            pr[r] += __shfl_xor(pr[r], 4); pr[r] += __shfl_xor(pr[r], 8);
        }
        if (coll == 0) {
            int part = (bn >> 6) + wc;
            #pragma unroll
            for (int r = 0; r < 4; r++)
                xsp[(size_t)part * N0_ + rowb + r] = pr[r];
        }
    }
}

// ---- stage 0: fused CSR build + aggregation; CSR kept in LDS for the agg phase ----
__global__ __launch_bounds__(1024) void csr_agg0_k(
        const float* __restrict__ X, const int* __restrict__ esrc, const int* __restrict__ edst,
        int* __restrict__ offs, int* __restrict__ offe, int* __restrict__ csrc,
        float* __restrict__ coef, float* __restrict__ dinv,
        bf16* __restrict__ AHo, bf16* __restrict__ ALo) {
    extern __shared__ float lds[];
    float* xs   = lds;                       // 200*128
    int* ecache = (int*)(xs + NPG_ * 128);   // SLOTG
    int* cnt    = ecache + SLOTG;            // 256
    int* scn    = cnt + 256;
    int* pos    = scn + 256;
    float* dv   = (float*)(pos + 256);
    int* offsL  = (int*)(dv + 256);
    int* offeL  = offsL + 256;
    int* csrcL  = offeL + 256;               // <= 3800 (local idx, sign bit = pad)
    int g = xcd_swz(blockIdx.x, B_);
    int t = threadIdx.x;
    int ebase = g * SLOTG, nb0 = g * NPG_, obase = g * 256, cbase = g * CSTRIDE;
    if (t < 256) cnt[t] = 0;
    __syncthreads();
    for (int i = t; i < NPG_ * 32; i += 1024) {
        int row = i >> 5, c4 = i & 31;
        ((float4*)xs)[i] = *(const float4*)&X[(size_t)(nb0 + row) * FIN_ + (c4 << 2)];
    }
    for (int e = t; e < SLOTG; e += 1024) {
        int cs_l = esrc[ebase + e] - nb0;
        int cd_l = edst[ebase + e] - nb0;
        ecache[e] = cs_l | (cd_l << 8);
        atomicAdd(&cnt[cd_l], 1);
    }
    __syncthreads();
    int v = 0, vp = 0;
    if (t < 256) {
        v = (t < NPG_) ? cnt[t] : 0;
        dv[t] = rsqrtf((float)v + 1.0f);
        vp = (v + 3) & ~3;
        scn[t] = vp;
    }
    __syncthreads();
    for (int d = 1; d < 256; d <<= 1) {
        int u = (t < 256 && t >= d) ? scn[t - d] : 0;
        __syncthreads();
        if (t < 256) scn[t] += u;
        __syncthreads();
    }
    if (t < 256) {
        int excl = scn[t] - vp;
        pos[t] = excl;
        offsL[t] = excl; offeL[t] = excl + vp;
        if (t < NPG_) {
            offs[obase + t] = cbase + excl;
            offe[obase + t] = cbase + excl + vp;
            dinv[obase + t] = dv[t];
            for (int p = v; p < vp; p++) {
                csrc[cbase + excl + p] = nb0 + t; coef[cbase + excl + p] = 0.f;
                csrcL[excl + p] = t | (int)0x80000000;
            }
        }
    }
    __syncthreads();
    for (int e = t; e < SLOTG; e += 1024) {
        int pk = ecache[e];
        int cs_l = pk & 255, cd_l = pk >> 8;
        int p = atomicAdd(&pos[cd_l], 1);
        csrc[cbase + p] = nb0 + cs_l;
        coef[cbase + p] = dv[cd_l] * dv[cs_l];
        csrcL[p] = cs_l;
    }
    __syncthreads();
    int wid = t >> 6, lane = t & 63;
    const float2* ld2 = (const float2*)xs;      // row stride 64 float2
    for (int nl = wid; nl < NPG_; nl += 16) {
        float ddv = dv[nl];
        int e0 = offsL[nl], e1 = offeL[nl];
        float ax = 0.f, ay = 0.f;
        for (int j = e0; j < e1; j += 4) {
            int4 s4 = *(const int4*)&csrcL[j];
            float c0 = (s4.x >= 0) ? ddv * dv[s4.x & 255] : 0.f;
            float c1 = (s4.y >= 0) ? ddv * dv[s4.y & 255] : 0.f;
            float c2 = (s4.z >= 0) ? ddv * dv[s4.z & 255] : 0.f;
            float c3 = (s4.w >= 0) ? ddv * dv[s4.w & 255] : 0.f;
            float2 v0 = ld2[(s4.x & 255) * 64 + lane];
            float2 v1 = ld2[(s4.y & 255) * 64 + lane];
            float2 v2 = ld2[(s4.z & 255) * 64 + lane];
            float2 v3 = ld2[(s4.w & 255) * 64 + lane];
            ax += c0 * v0.x + c1 * v1.x + c2 * v2.x + c3 * v3.x;
            ay += c0 * v0.y + c1 * v1.y + c2 * v2.y + c3 * v3.y;
        }
        float2 self = ld2[nl * 64 + lane];
        float s2 = ddv * ddv;
        ax += s2 * self.x; ay += s2 * self.y;
        write_split2(AHo, ALo, (size_t)(nb0 + nl) * FIN_ + lane * 2, ax, ay);
    }
}

// ---- fused: score+topk+pool+readout(stage s) THEN csr+agg(stage s+1), CSR in LDS ----
__global__ __launch_bounds__(1024) void stp_csr_agg_k(
        const float* __restrict__ Hb, const float* __restrict__ xsp,
        int* __restrict__ offs, int* __restrict__ offe, int* __restrict__ csrc,
        float* __restrict__ coef, float* __restrict__ dinv, const float* __restrict__ bs,
        const int* __restrict__ esrc, const int* __restrict__ edst,
        int* __restrict__ curmap, float* __restrict__ z,
        bf16* __restrict__ AHo, bf16* __restrict__ ALo,
        int npgA, int kA, int accumulate, int identCur) {
    extern __shared__ float lds[];
    float* xs   = lds;                        // kA*256 (pooled features)
    int* ecache = (int*)(xs + kA * 256);      // SLOTG
    int* cml    = ecache + SLOTG;             // 256
    int* cnt    = cml + 256;
    int* scn    = cnt + 256;
    int* pos    = scn + 256;
    float* dv   = (float*)(pos + 256);
    float* xsl  = dv + 256;
    float* sco  = xsl + 256;
    int* idx    = (int*)(sco + 256);
    int* rl     = idx + 256;
    int* ps     = rl + 256;                   // 128
    float* ts   = (float*)(ps + 128);         // 128
    float* pred = ts + 128;                   // 2048
    int* offsL  = (int*)(pred + 2048);
    int* offeL  = offsL + 256;
    int* csrcL  = offeL + 256;                // <= SLOTG + 3*kA
    int g = xcd_swz(blockIdx.x, B_);
    int t = threadIdx.x;
    int nb0 = g * npgA, ob0 = g * NPG_, obase = g * 256;
    // ---- phase A: score GCN ----
    if (t < 256) {
        float xv = 0.f;
        if (t < npgA) {
            int gi = nb0 + t;
            xv = xsp[gi] + xsp[N0_ + gi] + xsp[2 * N0_ + gi] + xsp[3 * N0_ + gi];
        }
        xsl[t] = xv;
        rl[t] = -1;
        cnt[t] = 0;
    }
    __syncthreads();
    if (t < 256) {
        float scv = -INFINITY;
        if (t < npgA) {
            float dd = dinv[obase + t];
            float acc = 0.f;
            for (int j = offs[obase + t]; j < offe[obase + t]; j++)
                acc += coef[j] * xsl[csrc[j] - nb0];
            scv = acc + xsl[t] * dd * dd + bs[0];
        }
        sco[t] = scv;
        idx[t] = (t < npgA) ? t : 0x7fffffff;
    }
    __syncthreads();
    // ---- bitonic top-k ----
    for (int ksz = 2; ksz <= 256; ksz <<= 1) {
        for (int j = ksz >> 1; j > 0; j >>= 1) {
            int ixj = t ^ j;
            if (t < 256 && ixj > t) {
                float s1 = sco[t], s2 = sco[ixj];
                int i1 = idx[t], i2 = idx[ixj];
                bool asc = ((t & ksz) == 0);
                bool agtb = (s1 < s2) || (s1 == s2 && i1 > i2);
                if (asc ? agtb : !agtb) { sco[t] = s2; sco[ixj] = s1; idx[t] = i2; idx[ixj] = i1; }
            }
            __syncthreads();
        }
    }
    if (t < kA) {
        rl[idx[t]] = g * kA + t;
        ps[t] = nb0 + idx[t];
        ts[t] = tanhf(sco[t]);
    }
    __syncthreads();
    // ---- pool into LDS + partial readout (all 1024 threads) ----
    {
        int f = t & 255, grp = t >> 8;
        float mx = -INFINITY, sm = 0.f;
        for (int j = grp; j < kA; j += 4) {
            float v = Hb[(size_t)ps[j] * H_ + f] * ts[j];
            xs[j * 256 + f] = v;
            mx = fmaxf(mx, v); sm += v;
        }
        pred[grp * 256 + f] = mx;
        pred[1024 + grp * 256 + f] = sm;
    }
    __syncthreads();
    // ---- readout reduce + curmap compose ----
    if (t < 256) {
        float mx = fmaxf(fmaxf(pred[t], pred[256 + t]), fmaxf(pred[512 + t], pred[768 + t]));
        float sm = pred[1024 + t] + pred[1280 + t] + pred[1536 + t] + pred[1792 + t];
        float mean = sm / (float)kA;
        if (accumulate) { z[g * 512 + t] += mx; z[g * 512 + 256 + t] += mean; }
        else            { z[g * 512 + t]  = mx; z[g * 512 + 256 + t]  = mean; }
        int nl = -1;
        if (t < NPG_) {
            int oldl;
            if (identCur) oldl = t;
            else { int gc = curmap[ob0 + t]; oldl = (gc < 0) ? -1 : gc - nb0; }
            nl = (oldl < 0) ? -1 : rl[oldl];
            curmap[ob0 + t] = nl;
        }
        cml[t] = nl;
    }
    __syncthreads();
    // ---- phase B: CSR build for new stage (npg_new = kA), mirrored into LDS ----
    int nb0n = g * kA, cbase = g * CSTRIDE;
    for (int e = t; e < SLOTG; e += 1024) {
        int cs = cml[esrc[g * SLOTG + e] - ob0];
        int cd = cml[edst[g * SLOTG + e] - ob0];
        int pk = -1;
        if (cs >= 0 && cd >= 0) {
            int cs_l = cs - nb0n, cd_l = cd - nb0n;
            pk = cs_l | (cd_l << 8);
            atomicAdd(&cnt[cd_l], 1);
        }
        ecache[e] = pk;
    }
    __syncthreads();
    int v = 0, vp = 0;
    if (t < 256) {
        v = (t < kA) ? cnt[t] : 0;
        dv[t] = rsqrtf((float)v + 1.0f);
        vp = (v + 3) & ~3;
        scn[t] = vp;
    }
    __syncthreads();
    for (int d = 1; d < 256; d <<= 1) {
        int u = (t < 256 && t >= d) ? scn[t - d] : 0;
        __syncthreads();
        if (t < 256) scn[t] += u;
        __syncthreads();
    }
    if (t < 256) {
        int excl = scn[t] - vp;
        pos[t] = excl;
        offsL[t] = excl; offeL[t] = excl + vp;
        if (t < kA) {
            offs[obase + t] = cbase + excl;
            offe[obase + t] = cbase + excl + vp;
            dinv[obase + t] = dv[t];
            for (int p = v; p < vp; p++) {
                csrc[cbase + excl + p] = nb0n + t; coef[cbase + excl + p] = 0.f;
                csrcL[excl + p] = t | (int)0x80000000;
            }
        }
    }
    __syncthreads();
    for (int e = t; e < SLOTG; e += 1024) {
        int pk = ecache[e];
        if (pk >= 0) {
            int cs_l = pk & 255, cd_l = pk >> 8;
            int p = atomicAdd(&pos[cd_l], 1);
            csrc[cbase + p] = nb0n + cs_l;
            coef[cbase + p] = dv[cd_l] * dv[cs_l];
            csrcL[p] = cs_l;
        }
    }
    __syncthreads();
    // ---- phase C: aggregation of pooled features (FI = 256), all-LDS ----
    int wid = t >> 6, lane = t & 63;
    const float4* ld4 = (const float4*)xs;      // row stride 64 float4
    for (int nl2 = wid; nl2 < kA; nl2 += 16) {
        float ddv = dv[nl2];
        int e0 = offsL[nl2], e1 = offeL[nl2];
        float ax = 0.f, ay = 0.f, az = 0.f, aw = 0.f;
        for (int j = e0; j < e1; j += 4) {
            int4 s4 = *(const int4*)&csrcL[j];
            float c0 = (s4.x >= 0) ? ddv * dv[s4.x & 255] : 0.f;
            float c1 = (s4.y >= 0) ? ddv * dv[s4.y & 255] : 0.f;
            float c2 = (s4.z >= 0) ? ddv * dv[s4.z & 255] : 0.f;
            float c3 = (s4.w >= 0) ? ddv * dv[s4.w & 255] : 0.f;
            float4 v0 = ld4[(s4.x & 255) * 64 + lane];
            float4 v1 = ld4[(s4.y & 255) * 64 + lane];
            float4 v2 = ld4[(s4.z & 255) * 64 + lane];
            float4 v3 = ld4[(s4.w & 255) * 64 + lane];
            ax += c0 * v0.x + c1 * v1.x + c2 * v2.x + c3 * v3.x;
            ay += c0 * v0.y + c1 * v1.y + c2 * v2.y + c3 * v3.y;
            az += c0 * v0.z + c1 * v1.z + c2 * v2.z + c3 * v3.z;
            aw += c0 * v0.w + c1 * v1.w + c2 * v2.w + c3 * v3.w;
        }
        float4 self = ld4[nl2 * 64 + lane];
        float s2 = ddv * ddv;
        ax += s2 * self.x; ay += s2 * self.y; az += s2 * self.z; aw += s2 * self.w;
        write_split4(AHo, ALo, (size_t)(nb0n + nl2) * H_ + lane * 4, ax, ay, az, aw);
    }
}

// ---- fused final tail: score + topk + readout + whole MLP + log_softmax ----
__global__ __launch_bounds__(256) void stp_mlp_k(
        const float* __restrict__ Hb, const float* __restrict__ xsp,
        const int* __restrict__ offs, const int* __restrict__ offe,
        const int* __restrict__ csrc, const float* __restrict__ coef,
        const float* __restrict__ dinv, const float* __restrict__ bs,
        const float* __restrict__ Z,
        const float* __restrict__ Wl1, const float* __restrict__ bl1,
        const float* __restrict__ Wl2, const float* __restrict__ bl2,
        const float* __restrict__ Wl3, const float* __restrict__ bl3,
        float* __restrict__ out, int npgA, int kA) {
    __shared__ float xsl[256];
    __shared__ float sco[256];
    __shared__ int   idx[256];
    __shared__ int   ps[128];
    __shared__ float ts[128];
    __shared__ float zin[512];
    __shared__ float h1[256];
    __shared__ float h2[128];
    int g = xcd_swz(blockIdx.x, B_);
    int t = threadIdx.x;
    int nb0 = g * npgA, obase = g * 256;
    float xv = 0.f;
    if (t < npgA) {
        int gi = nb0 + t;
        xv = xsp[gi] + xsp[N0_ + gi] + xsp[2 * N0_ + gi] + xsp[3 * N0_ + gi];
    }
    xsl[t] = xv;
    __syncthreads();
    float scv = -INFINITY;
    if (t < npgA) {
        float dd = dinv[obase + t];
        float acc = 0.f;
        for (int j = offs[obase + t]; j < offe[obase + t]; j++)
            acc += coef[j] * xsl[csrc[j] - nb0];
        scv = acc + xsl[t] * dd * dd + bs[0];
    }
    sco[t] = scv;
    idx[t] = (t < npgA) ? t : 0x7fffffff;
    __syncthreads();
    for (int ksz = 2; ksz <= 256; ksz <<= 1) {
        for (int j = ksz >> 1; j > 0; j >>= 1) {
            int ixj = t ^ j;
            if (ixj > t) {
                float s1 = sco[t], s2 = sco[ixj];
                int i1 = idx[t], i2 = idx[ixj];
                bool asc = ((t & ksz) == 0);
                bool agtb = (s1 < s2) || (s1 == s2 && i1 > i2);
                if (asc ? agtb : !agtb) { sco[t] = s2; sco[ixj] = s1; idx[t] = i2; idx[ixj] = i1; }
            }
            __syncthreads();
        }
    }
    if (t < kA) { ps[t] = nb0 + idx[t]; ts[t] = tanhf(sco[t]); }
    __syncthreads();
    float mx = -INFINITY, sm = 0.f;
    for (int j = 0; j < kA; j++) {
        float v = Hb[(size_t)ps[j] * H_ + t] * ts[j];
        mx = fmaxf(mx, v); sm += v;
    }
    zin[t]       = Z[g * 512 + t] + mx;
    zin[256 + t] = Z[g * 512 + 256 + t] + sm / (float)kA;
    __syncthreads();
    // MLP layer 1
    float a = bl1[t];
    for (int k = 0; k < 512; k++) a += zin[k] * Wl1[k * 256 + t];
    h1[t] = fmaxf(a, 0.f);
    __syncthreads();
    if (t < 128) {
        float a2 = bl2[t];
        for (int k = 0; k < 256; k++) a2 += h1[k] * Wl2[k * 128 + t];
        h2[t] = fmaxf(a2, 0.f);
    }
    __syncthreads();
    if (t < 64) {
        float a0 = h2[t], a1 = h2[t + 64];
        float r[10];
        #pragma unroll
        for (int n = 0; n < 10; n++) r[n] = a0 * Wl3[t * 10 + n] + a1 * Wl3[(t + 64) * 10 + n];
        #pragma unroll
        for (int d = 1; d < 64; d <<= 1)
            #pragma unroll
            for (int n = 0; n < 10; n++) r[n] += __shfl_xor(r[n], d);
        float v[10]; float mxv = -INFINITY;
        #pragma unroll
        for (int n = 0; n < 10; n++) { v[n] = r[n] + bl3[n]; mxv = fmaxf(mxv, v[n]); }
        float s = 0.f;
        #pragma unroll
        for (int n = 0; n < 10; n++) s += expf(v[n] - mxv);
        float ls = logf(s);
        if (t < 10) out[g * 10 + t] = v[t] - mxv - ls;
    }
}

extern "C" void kernel_launch(void* const* d_in, const int* in_sizes, int n_in,
                              void* d_out, int out_size, void* d_ws, size_t ws_size,
                              hipStream_t stream) {
    const float* x   = (const float*)d_in[0];
    const int*  esrc = (const int*) d_in[1];
    const int*  edst = (const int*) d_in[2];
    const float *W1 = (const float*)d_in[3],  *b1 = (const float*)d_in[4];
    const float *Ws1= (const float*)d_in[5],  *bs1= (const float*)d_in[6];
    const float *W2 = (const float*)d_in[7],  *b2 = (const float*)d_in[8];
    const float *Ws2= (const float*)d_in[9],  *bs2= (const float*)d_in[10];
    const float *W3 = (const float*)d_in[11], *b3 = (const float*)d_in[12];
    const float *Ws3= (const float*)d_in[13], *bs3= (const float*)d_in[14];
    const float *Wl1= (const float*)d_in[15], *bl1= (const float*)d_in[16];
    const float *Wl2= (const float*)d_in[17], *bl2= (const float*)d_in[18];
    const float *Wl3= (const float*)d_in[19], *bl3= (const float*)d_in[20];
    float* out = (float*)d_out;

    // ---- workspace layout ----
    float* ws = (float*)d_ws;
    float* Hb    = ws;                         // N0*H f32
    float* XSP   = Hb + (size_t)N0_ * H_;      // 4*N0
    int*   OFFS  = (int*)(XSP + 4 * N0_);      // B*256
    int*   OFFE  = OFFS + B_ * 256;            // B*256
    float* DINV  = (float*)(OFFE + B_ * 256);  // B*256
    int*   CURMAP= (int*)(DINV + B_ * 256);    // N0
    int*   CSRC  = CURMAP + N0_;               // CSRN
    float* COEF  = (float*)(CSRC + CSRN);      // CSRN
    float* Z     = COEF + CSRN;                // B*512
    bf16*  AH    = (bf16*)(Z + B_ * 512);      // N0*H bf16
    bf16*  AL    = AH + (size_t)N0_ * H_;      // N0*H bf16
    bf16*  WTH   = AL + (size_t)N0_ * H_;      // 3 * 256*256 bf16
    bf16*  WTL   = WTH + 3 * 256 * 256;        // 3 * 256*256 bf16

    // 1. weight convert (all 3 stages)
    wconv_k<<<dim3(8, 8, 3), 256, 0, stream>>>(W1, W2, W3, WTH, WTL);

    // 2. stage-0 CSR + aggregation fused (CSR mirrored in LDS)
    size_t lds0 = (size_t)(NPG_ * 128 + SLOTG + 4 * 256 + 2 * 256 + (SLOTG + 3 * NPG_ + 8)) * 4;
    csr_agg0_k<<<B_, 1024, lds0, stream>>>(x, esrc, edst, OFFS, OFFE, CSRC, COEF, DINV, AH, AL);

    // 3. gemm stage 0 (K=128)
    gemm_mfma<<<dim3(N0_ / 64, 2), 256, 0, stream>>>(
        AH, AL, WTH, WTL, b1, Ws1, Hb, XSP, N0_, FIN_, H_);

    // 4. stp(stage0) + csr+agg(stage1) fused
    auto stp_lds = [](int kA) {
        return (size_t)(kA * 256 + SLOTG + 5 * 256 + 4 * 256 + 2 * 128 + 2048 + 2 * 256 +
                        ((SLOTG + 3 * kA + 15) & ~15)) * 4;
    };
    stp_csr_agg_k<<<B_, 1024, stp_lds(K1_), stream>>>(
        Hb, XSP, OFFS, OFFE, CSRC, COEF, DINV, bs1, esrc, edst, CURMAP, Z, AH, AL,
        NPG_, K1_, 0, 1);

    // 5. gemm stage 1 (K=256)
    gemm_mfma<<<dim3(B_ * K1_ / 64, 2), 256, 0, stream>>>(
        AH, AL, WTH + 65536, WTL + 65536, b2, Ws2, Hb, XSP, B_ * K1_, H_, H_);

    // 6. stp(stage1) + csr+agg(stage2) fused
    stp_csr_agg_k<<<B_, 1024, stp_lds(K2_), stream>>>(
        Hb, XSP, OFFS, OFFE, CSRC, COEF, DINV, bs2, esrc, edst, CURMAP, Z, AH, AL,
        K1_, K2_, 1, 0);

    // 7. gemm stage 2 (K=256)
    gemm_mfma<<<dim3(B_ * K2_ / 64, 2), 256, 0, stream>>>(
        AH, AL, WTH + 2 * 65536, WTL + 2 * 65536, b3, Ws3, Hb, XSP, B_ * K2_, H_, H_);

    // 8. final score + topk + readout + MLP + log_softmax
    stp_mlp_k<<<B_, 256, 0, stream>>>(Hb, XSP, OFFS, OFFE, CSRC, COEF, DINV, bs3, Z,
                                      Wl1, bl1, Wl2, bl2, Wl3, bl3, out, K2_, K3_);
}

// Round 13
// 163.891 us; speedup vs baseline: 1.1964x; 1.1964x over previous
//
#include <hip/hip_runtime.h>
#include <hip/hip_bf16.h>
#include <math.h>

typedef __hip_bfloat16 bf16;
typedef __attribute__((ext_vector_type(8))) short bf16x8;
typedef __attribute__((ext_vector_type(4))) float f32x4;

#define B_   256
#define NPG_ 200
#define N0_  (B_*NPG_)
#define DEGC 16
#define SLOTG (NPG_*DEGC)   // 3200 edge slots per graph (original layout)
#define FIN_ 128
#define H_   256

// ---- LDS arena layout (bytes) ----
#define ARENA_OFF   0           // float[26400]: X [200][132] or pooled [k][260]
#define BSLAB_OFF   105600      // bf16 hi[8192] + lo[8192] (4 kg x 256 col x 8)
#define CSRCL_OFF   138368      // ushort[3200]
#define OFFSL_OFF   144768      // int[256]
#define OFFEL_OFF   145792      // int[256]
#define DV_OFF      146816      // float[256]
#define CNT_OFF     147840      // int[256]
#define SCN_OFF     148864      // int[256]
#define POS_OFF     149888      // int[256]
#define CML_OFF     150912      // int[256]
#define XSL_OFF     151936      // float[256]
#define SCO_OFF     152960      // float[256]
#define IDX_OFF     153984      // int[256]
#define RL_OFF      155008      // int[256]
#define TS_OFF      156032      // float[128]
#define ZLDS_OFF    156544      // float[512]
#define LDS_TOTAL   158592

__device__ __forceinline__ unsigned int bfu(bf16 h) {
    return (unsigned int)*reinterpret_cast<unsigned short*>(&h);
}

__device__ __forceinline__ void split8(const float a[8], bf16x8& ah, bf16x8& al) {
    #pragma unroll
    for (int i = 0; i < 8; i++) {
        float v = a[i];
        bf16 h = __float2bfloat16(v);
        float rem = v - __bfloat162float(h);
        bf16 l = __float2bfloat16(rem);
        ah[i] = (short)bfu(h);
        al[i] = (short)bfu(l);
    }
}

// ---- batched W convert: W[K][N] f32 -> WT hi/lo bf16 [N][K], all 3 stages ----
__global__ void wconv_k(const float* __restrict__ W1, const float* __restrict__ W2,
                        const float* __restrict__ W3, bf16* __restrict__ THb,
                        bf16* __restrict__ TLb) {
    __shared__ float tile[32][33];
    int st = blockIdx.z;
    const float* W = st == 0 ? W1 : (st == 1 ? W2 : W3);
    int K = st == 0 ? 128 : 256;
    int N = 256;
    int k0 = blockIdx.x * 32, n0 = blockIdx.y * 32;
    if (k0 >= K) return;
    bf16* TH = THb + st * 65536;
    bf16* TL = TLb + st * 65536;
    int t = threadIdx.x;
    int tc = t & 31, tr = t >> 5;
    #pragma unroll
    for (int i = 0; i < 4; i++) {
        int kk = tr + i * 8;
        tile[kk][tc] = W[(size_t)(k0 + kk) * N + n0 + tc];
    }
    __syncthreads();
    #pragma unroll
    for (int i = 0; i < 4; i++) {
        int nn = tr + i * 8;
        float v = tile[tc][nn];
        bf16 h = __float2bfloat16(v);
        TH[(size_t)(n0 + nn) * K + k0 + tc] = h;
        TL[(size_t)(n0 + nn) * K + k0 + tc] = __float2bfloat16(v - __bfloat162float(h));
    }
}

// ---- the mega kernel: one block per graph, full network ----
__global__ __launch_bounds__(512) void mega_k(
        const float* __restrict__ X, const int* __restrict__ esrc, const int* __restrict__ edst,
        const bf16* __restrict__ WTH, const bf16* __restrict__ WTL,
        const float* __restrict__ b1, const float* __restrict__ b2, const float* __restrict__ b3,
        const float* __restrict__ Ws1, const float* __restrict__ Ws2, const float* __restrict__ Ws3,
        const float* __restrict__ bs1, const float* __restrict__ bs2, const float* __restrict__ bs3,
        const float* __restrict__ Wl1, const float* __restrict__ bl1,
        const float* __restrict__ Wl2, const float* __restrict__ bl2,
        const float* __restrict__ Wl3, const float* __restrict__ bl3,
        float* __restrict__ out) {
    extern __shared__ char lds[];
    float*          arena = (float*)(lds + ARENA_OFF);
    bf16*           lBhi  = (bf16*)(lds + BSLAB_OFF);
    bf16*           lBlo  = lBhi + 8192;
    unsigned short* csrcL = (unsigned short*)(lds + CSRCL_OFF);
    int*            offsL = (int*)(lds + OFFSL_OFF);
    int*            offeL = (int*)(lds + OFFEL_OFF);
    float*          dv    = (float*)(lds + DV_OFF);
    int*            cnt   = (int*)(lds + CNT_OFF);
    int*            scn   = (int*)(lds + SCN_OFF);
    int*            pos   = (int*)(lds + POS_OFF);
    int*            cml   = (int*)(lds + CML_OFF);
    float*          xsl   = (float*)(lds + XSL_OFF);
    float*          sco   = (float*)(lds + SCO_OFF);
    int*            idx   = (int*)(lds + IDX_OFF);
    int*            rl    = (int*)(lds + RL_OFF);
    float*          ts    = (float*)(lds + TS_OFF);
    float*          zlds  = (float*)(lds + ZLDS_OFF);

    int g = blockIdx.x;
    int t = threadIdx.x;
    int w = t >> 6, lane = t & 63;
    int coll = lane & 15, kgq = lane >> 4;
    int ob0 = g * NPG_;
    int ebase = g * SLOTG;

    zlds[t] = 0.0f;
    if (t < 256) cml[t] = (t < NPG_) ? t : -1;

    // stage-0 X load: [200][128] f32 -> arena stride 132 (33 float4/row)
    {
        const float4* src = (const float4*)(X + (size_t)ob0 * FIN_);
        float4* dst = (float4*)arena;
        for (int i = t; i < NPG_ * 32; i += 512) {
            int row = i >> 5, c4 = i & 31;
            dst[row * 33 + c4] = src[i];
        }
    }

    for (int st = 0; st < 3; st++) {
        const int npg = (st == 0) ? 200 : (st == 1 ? 100 : 50);
        const int kA  = (st == 0) ? 100 : (st == 1 ? 50 : 25);
        const int FI  = (st == 0) ? 128 : 256;
        const int MT  = (st == 0) ? 13 : (st == 1 ? 7 : 4);
        const int strideF = (st == 0) ? 132 : 260;
        const int KS  = FI / 32;
        const bf16* BTH = WTH + st * 65536;
        const bf16* BTL = WTL + st * 65536;
        const float* bias = (st == 0) ? b1 : (st == 1 ? b2 : b3);
        const float* Wsd  = (st == 0) ? Ws1 : (st == 1 ? Ws2 : Ws3);
        const float* bsp  = (st == 0) ? bs1 : (st == 1 ? bs2 : bs3);

        if (t < 256) { cnt[t] = 0; rl[t] = -1; }
        __syncthreads();

        // ---- edge pass 1: degree count (via cml) ----
        for (int e = t; e < SLOTG; e += 512) {
            int cs = cml[esrc[ebase + e] - ob0];
            int cd = cml[edst[ebase + e] - ob0];
            if (cs >= 0 && cd >= 0) atomicAdd(&cnt[cd], 1);
        }
        __syncthreads();

        // ---- scan (exclusive) + dv ----
        int v = 0;
        if (t < 256) {
            v = (t < npg) ? cnt[t] : 0;
            dv[t] = rsqrtf((float)v + 1.0f);
            scn[t] = v;
        }
        __syncthreads();
        for (int d = 1; d < 256; d <<= 1) {
            int u = (t < 256 && t >= d) ? scn[t - d] : 0;
            __syncthreads();
            if (t < 256) scn[t] += u;
            __syncthreads();
        }
        if (t < 256) {
            int excl = scn[t] - v;
            offsL[t] = excl; offeL[t] = excl + v; pos[t] = excl;
        }
        __syncthreads();

        // ---- edge pass 2: scatter local src ids ----
        for (int e = t; e < SLOTG; e += 512) {
            int cs = cml[esrc[ebase + e] - ob0];
            int cd = cml[edst[ebase + e] - ob0];
            if (cs >= 0 && cd >= 0) {
                int p = atomicAdd(&pos[cd], 1);
                csrcL[p] = (unsigned short)cs;
            }
        }
        __syncthreads();

        // ---- GEMM: h = relu(Agg(X) @ W + bias); agg fused into A-frag load ----
        f32x4 acc[2][16] = {};
        for (int ks = 0; ks < KS; ks++) {
            // stage B k-slab (hi+lo) cooperatively: chunk-major [kg][col][8]
            for (int it = 0; it < 4; it++) {
                int c = t + it * 512;          // 0..2047
                int arr = c >> 10, id2 = c & 1023;
                int col = id2 >> 2, kg = id2 & 3;
                const bf16* src = (arr ? BTL : BTH) + (size_t)col * FI + ks * 32 + kg * 8;
                bf16* dst = (arr ? lBlo : lBhi) + kg * 2048 + col * 8;
                *(uint4*)dst = *(const uint4*)src;
            }
            __syncthreads();
            #pragma unroll
            for (int rep = 0; rep < 2; rep++) {
                int mt = w + rep * 8;
                if (mt < MT) {
                    int rL = mt * 16 + coll;
                    int kbase = ks * 32 + kgq * 8;
                    float a8[8] = {0.f,0.f,0.f,0.f,0.f,0.f,0.f,0.f};
                    if (rL < npg) {
                        float ddv = dv[rL];
                        int e0 = offsL[rL], e1 = offeL[rL];
                        for (int j = e0; j < e1; j++) {
                            int s = csrcL[j];
                            float cf = ddv * dv[s];
                            const float* xr = arena + s * strideF + kbase;
                            float4 xa = *(const float4*)xr;
                            float4 xb = *(const float4*)(xr + 4);
                            a8[0] += cf * xa.x; a8[1] += cf * xa.y;
                            a8[2] += cf * xa.z; a8[3] += cf * xa.w;
                            a8[4] += cf * xb.x; a8[5] += cf * xb.y;
                            a8[6] += cf * xb.z; a8[7] += cf * xb.w;
                        }
                        float cf = ddv * ddv;
                        const float* xr = arena + rL * strideF + kbase;
                        float4 xa = *(const float4*)xr;
                        float4 xb = *(const float4*)(xr + 4);
                        a8[0] += cf * xa.x; a8[1] += cf * xa.y;
                        a8[2] += cf * xa.z; a8[3] += cf * xa.w;
                        a8[4] += cf * xb.x; a8[5] += cf * xb.y;
                        a8[6] += cf * xb.z; a8[7] += cf * xb.w;
                    }
                    bf16x8 ah, al;
                    split8(a8, ah, al);
                    #pragma unroll
                    for (int nt = 0; nt < 16; nt++) {
                        int col = nt * 16 + coll;
                        bf16x8 bh = *(const bf16x8*)&lBhi[kgq * 2048 + col * 8];
                        bf16x8 bl = *(const bf16x8*)&lBlo[kgq * 2048 + col * 8];
                        acc[rep][nt] = __builtin_amdgcn_mfma_f32_16x16x32_bf16(ah, bh, acc[rep][nt], 0, 0, 0);
                        acc[rep][nt] = __builtin_amdgcn_mfma_f32_16x16x32_bf16(ah, bl, acc[rep][nt], 0, 0, 0);
                        acc[rep][nt] = __builtin_amdgcn_mfma_f32_16x16x32_bf16(al, bh, acc[rep][nt], 0, 0, 0);
                    }
                }
            }
            __syncthreads();
        }

        // ---- epilogue: bias + relu in place, xs = h.Ws ----
        float bv[16], wsv[16];
        #pragma unroll
        for (int nt = 0; nt < 16; nt++) {
            int col = nt * 16 + coll;
            bv[nt] = bias[col];
            wsv[nt] = Wsd[col];
        }
        #pragma unroll
        for (int rep = 0; rep < 2; rep++) {
            int mt = w + rep * 8;
            if (mt < MT) {
                float pr[4] = {0.f, 0.f, 0.f, 0.f};
                #pragma unroll
                for (int nt = 0; nt < 16; nt++) {
                    #pragma unroll
                    for (int r = 0; r < 4; r++) {
                        float hv = fmaxf(acc[rep][nt][r] + bv[nt], 0.0f);
                        acc[rep][nt][r] = hv;
                        pr[r] += hv * wsv[nt];
                    }
                }
                #pragma unroll
                for (int r = 0; r < 4; r++) {
                    pr[r] += __shfl_xor(pr[r], 1); pr[r] += __shfl_xor(pr[r], 2);
                    pr[r] += __shfl_xor(pr[r], 4); pr[r] += __shfl_xor(pr[r], 8);
                }
                if (coll == 0) {
                    #pragma unroll
                    for (int r = 0; r < 4; r++) {
                        int rloc = mt * 16 + kgq * 4 + r;
                        if (rloc < npg) xsl[rloc] = pr[r];
                    }
                }
            }
        }
        __syncthreads();

        // ---- score GCN ----
        if (t < 256) {
            float scv = -INFINITY;
            if (t < npg) {
                float dd = dv[t];
                float a = 0.f;
                for (int j = offsL[t]; j < offeL[t]; j++) {
                    int s = csrcL[j];
                    a += dd * dv[s] * xsl[s];
                }
                scv = a + xsl[t] * dd * dd + bsp[0];
            }
            sco[t] = scv;
            idx[t] = (t < npg) ? t : 0x7fffffff;
        }
        __syncthreads();

        // ---- bitonic top-k sort by (-score, idx) ----
        for (int ksz = 2; ksz <= 256; ksz <<= 1) {
            for (int j = ksz >> 1; j > 0; j >>= 1) {
                int ixj = t ^ j;
                if (t < 256 && ixj > t) {
                    float s1 = sco[t], s2 = sco[ixj];
                    int i1 = idx[t], i2 = idx[ixj];
                    bool asc = ((t & ksz) == 0);
                    bool agtb = (s1 < s2) || (s1 == s2 && i1 > i2);
                    if (asc ? agtb : !agtb) { sco[t] = s2; sco[ixj] = s1; idx[t] = i2; idx[ixj] = i1; }
                }
                __syncthreads();
            }
        }
        if (t < kA) {
            rl[idx[t]] = t;
            ts[t] = tanhf(sco[t]);
        }
        __syncthreads();

        // ---- cml compose + pooling from acc regs into arena (stride 260) ----
        if (t < 256) {
            int old = cml[t];
            cml[t] = (old >= 0) ? rl[old] : -1;
        }
        #pragma unroll
        for (int rep = 0; rep < 2; rep++) {
            int mt = w + rep * 8;
            if (mt < MT) {
                #pragma unroll
                for (int r = 0; r < 4; r++) {
                    int rloc = mt * 16 + kgq * 4 + r;
                    int slot = (rloc < npg) ? rl[rloc] : -1;
                    if (slot >= 0) {
                        float tg = ts[slot];
                        #pragma unroll
                        for (int nt = 0; nt < 16; nt++)
                            arena[slot * 260 + nt * 16 + coll] = acc[rep][nt][r] * tg;
                    }
                }
            }
        }
        __syncthreads();

        // ---- readout gmp||gap into zlds ----
        if (t < 256) {
            float mx = -INFINITY, sm = 0.f;
            for (int j = 0; j < kA; j++) {
                float hv = arena[j * 260 + t];
                mx = fmaxf(mx, hv); sm += hv;
            }
            zlds[t] += mx;
            zlds[256 + t] += sm / (float)kA;
        }
        __syncthreads();
    }

    // ---- MLP head + log_softmax (reuse xsl as h1, sco as h2) ----
    float* h1 = xsl;
    float* h2 = sco;
    if (t < 256) {
        float a = bl1[t];
        for (int k = 0; k < 512; k++) a += zlds[k] * Wl1[k * 256 + t];
        h1[t] = fmaxf(a, 0.f);
    }
    __syncthreads();
    if (t < 128) {
        float a = bl2[t];
        for (int k = 0; k < 256; k++) a += h1[k] * Wl2[k * 128 + t];
        h2[t] = fmaxf(a, 0.f);
    }
    __syncthreads();
    if (t < 64) {
        float a0 = h2[t], a1 = h2[t + 64];
        float r[10];
        #pragma unroll
        for (int n = 0; n < 10; n++) r[n] = a0 * Wl3[t * 10 + n] + a1 * Wl3[(t + 64) * 10 + n];
        #pragma unroll
        for (int d = 1; d < 64; d <<= 1)
            #pragma unroll
            for (int n = 0; n < 10; n++) r[n] += __shfl_xor(r[n], d);
        float vv[10]; float mxv = -INFINITY;
        #pragma unroll
        for (int n = 0; n < 10; n++) { vv[n] = r[n] + bl3[n]; mxv = fmaxf(mxv, vv[n]); }
        float s = 0.f;
        #pragma unroll
        for (int n = 0; n < 10; n++) s += expf(vv[n] - mxv);
        float ls = logf(s);
        if (t < 10) out[g * 10 + t] = vv[t] - mxv - ls;
    }
}

extern "C" void kernel_launch(void* const* d_in, const int* in_sizes, int n_in,
                              void* d_out, int out_size, void* d_ws, size_t ws_size,
                              hipStream_t stream) {
    const float* x   = (const float*)d_in[0];
    const int*  esrc = (const int*) d_in[1];
    const int*  edst = (const int*) d_in[2];
    const float *W1 = (const float*)d_in[3],  *b1 = (const float*)d_in[4];
    const float *Ws1= (const float*)d_in[5],  *bs1= (const float*)d_in[6];
    const float *W2 = (const float*)d_in[7],  *b2 = (const float*)d_in[8];
    const float *Ws2= (const float*)d_in[9],  *bs2= (const float*)d_in[10];
    const float *W3 = (const float*)d_in[11], *b3 = (const float*)d_in[12];
    const float *Ws3= (const float*)d_in[13], *bs3= (const float*)d_in[14];
    const float *Wl1= (const float*)d_in[15], *bl1= (const float*)d_in[16];
    const float *Wl2= (const float*)d_in[17], *bl2= (const float*)d_in[18];
    const float *Wl3= (const float*)d_in[19], *bl3= (const float*)d_in[20];
    float* out = (float*)d_out;

    bf16* WTH = (bf16*)d_ws;                 // 3 * 256*256 bf16
    bf16* WTL = WTH + 3 * 65536;             // 3 * 256*256 bf16

    // 1. weight convert (all 3 stages)
    wconv_k<<<dim3(8, 8, 3), 256, 0, stream>>>(W1, W2, W3, WTH, WTL);

    // 2. whole network, one block per graph
    mega_k<<<B_, 512, LDS_TOTAL, stream>>>(
        x, esrc, edst, WTH, WTL,
        b1, b2, b3, Ws1, Ws2, Ws3, bs1, bs2, bs3,
        Wl1, bl1, Wl2, bl2, Wl3, bl3, out);
}